// Round 8
// baseline (247.217 us; speedup 1.0000x reference)
//
#include <hip/hip_runtime.h>
#include <math.h>

#define BB 64
#define SS 1024
#define VV 1024
#define DD 512

#define MAP_WORDS  ((long)BB * SS * VV)              // 67,108,864
#define STEP_WORDS ((long)BB * SS * SS)              // 67,108,864
#define TOT_WORDS  (MAP_WORDS + STEP_WORDS)          // 134,217,728
#define TOT_F4     (TOT_WORDS / 4)                   // 33,554,432
#define MAP_F4     (MAP_WORDS / 4)                   // 16,777,216

#define THREADS    256
#define NBLOCKS    ((int)(TOT_F4 / THREADS))         // 131072 (map/step split at blk 65536)
#define NGATES     (BB * 2)                          // 128

typedef float f32x4 __attribute__((ext_vector_type(4)));

__device__ __forceinline__ float gelu_tanh(float x) {
    const float k = 0.7978845608028654f; // sqrt(2/pi)
    float x3 = x * x * x;
    return 0.5f * x * (1.0f + tanhf(k * (x + 0.044715f * x3)));
}

// Monolithic: one f32x4 per thread (BabelStream shape). Each block screens
// the 128 candidate scatter targets (index needs no MLP); owner blocks
// (<=128 of 131072) compute their gate GEMV inline and fold the add.
__global__ void __launch_bounds__(THREADS)
copy_gate_scatter_kernel(
    const f32x4* __restrict__ map_memory,
    const f32x4* __restrict__ step_memory,
    f32x4* __restrict__ out,
    const float* __restrict__ evidence,
    const int* __restrict__ marker_id,
    const int* __restrict__ source_idx,
    const int* __restrict__ source_mask,
    const int* __restrict__ target_symbol_idx,
    const int* __restrict__ target_symbol_mask,
    const int* __restrict__ target_value_idx,
    const int* __restrict__ target_value_mask,
    const float* __restrict__ map_W1, const float* __restrict__ map_b1,
    const float* __restrict__ map_W2, const float* __restrict__ map_b2,
    const float* __restrict__ step_W1, const float* __restrict__ step_b1,
    const float* __restrict__ step_W2, const float* __restrict__ step_b2)
{
    const int blk = blockIdx.x;
    const int tid = threadIdx.x;

    __shared__ int nm;
    __shared__ int m_word[NGATES];   // word offset within block's 1024 words
    __shared__ int m_bh[NGATES];     // candidate id (b*2+head)
    __shared__ float m_g[NGATES];

    if (tid == 0) nm = 0;
    __syncthreads();

    // ---- screen the 128 candidates (pure index math, no MLP) ----
    if (tid < NGATES) {
        const int b = tid >> 1, head = tid & 1;
        const int m = marker_id[b];
        const bool sm = source_mask[b] != 0;
        long idx = -1;
        if (head == 0) {
            if (((m == 1) || (m == 2)) && sm && (target_value_mask[b] != 0))
                idx = (long)b * (SS * VV) + (long)source_idx[b] * VV
                    + target_value_idx[b];
        } else {
            if ((m == 3) && sm && (target_symbol_mask[b] != 0))
                idx = MAP_WORDS + (long)b * (SS * SS)
                    + (long)source_idx[b] * SS + target_symbol_idx[b];
        }
        if (idx >= 0 && (int)(idx >> 10) == blk) {   // 1024 words per block
            int slot = atomicAdd(&nm, 1);
            m_word[slot] = (int)(idx & 1023);
            m_bh[slot]   = tid;
        }
    }
    __syncthreads();
    const int nmatch = nm;

    // ---- owner blocks: compute their gate(s) inline ----
    if (nmatch) {
        __shared__ float ev[DD];
        __shared__ float wsum[4];
        for (int e = 0; e < nmatch; ++e) {
            const int bh = m_bh[e];
            const int b = bh >> 1, head = bh & 1;
            const float* W1  = head ? step_W1 : map_W1;
            const float* b1  = head ? step_b1 : map_b1;
            const float* W2  = head ? step_W2 : map_W2;
            const float* b2v = head ? step_b2 : map_b2;

            for (int i = tid; i < DD; i += THREADS) ev[i] = evidence[b * DD + i];
            __syncthreads();

            float acc = 0.0f;
            #pragma unroll
            for (int jj = 0; jj < DD; jj += THREADS) {
                const int j = jj + tid;
                float h = b1[j];
                #pragma unroll 8
                for (int k = 0; k < DD; ++k)
                    h = fmaf(ev[k], W1[k * DD + j], h);
                h = gelu_tanh(h);
                acc = fmaf(h, W2[j], acc);
            }
            #pragma unroll
            for (int off = 32; off > 0; off >>= 1)
                acc += __shfl_down(acc, off, 64);
            if ((tid & 63) == 0) wsum[tid >> 6] = acc;
            __syncthreads();
            if (tid == 0) {
                float g = wsum[0] + wsum[1] + wsum[2] + wsum[3] + b2v[0];
                m_g[e] = 1.0f / (1.0f + expf(-g));
            }
            __syncthreads();
        }
    }

    // ---- the copy: exactly one f32x4 per thread ----
    const long f4 = (long)blk * THREADS + tid;
    f32x4 v = (blk < NBLOCKS / 2) ? map_memory[f4]
                                  : step_memory[f4 - MAP_F4];
    if (nmatch) {
        for (int e = 0; e < nmatch; ++e) {
            if ((m_word[e] >> 2) == tid) {
                const int ln = m_word[e] & 3;
                const float g = m_g[e];
                v.x += (ln == 0) ? g : 0.0f;
                v.y += (ln == 1) ? g : 0.0f;
                v.z += (ln == 2) ? g : 0.0f;
                v.w += (ln == 3) ? g : 0.0f;
            }
        }
    }
    out[f4] = v;
}

extern "C" void kernel_launch(void* const* d_in, const int* in_sizes, int n_in,
                              void* d_out, int out_size, void* d_ws, size_t ws_size,
                              hipStream_t stream) {
    const float* map_memory  = (const float*)d_in[0];
    const float* step_memory = (const float*)d_in[1];
    const float* evidence    = (const float*)d_in[2];
    const int* marker_id     = (const int*)d_in[3];
    const int* source_idx    = (const int*)d_in[4];
    const int* source_mask        = (const int*)d_in[5];
    const int* target_symbol_idx  = (const int*)d_in[6];
    const int* target_symbol_mask = (const int*)d_in[7];
    const int* target_value_idx   = (const int*)d_in[8];
    const int* target_value_mask  = (const int*)d_in[9];
    const float* map_W1  = (const float*)d_in[10];
    const float* map_b1  = (const float*)d_in[11];
    const float* map_W2  = (const float*)d_in[12];
    const float* map_b2  = (const float*)d_in[13];
    const float* step_W1 = (const float*)d_in[14];
    const float* step_b1 = (const float*)d_in[15];
    const float* step_W2 = (const float*)d_in[16];
    const float* step_b2 = (const float*)d_in[17];

    copy_gate_scatter_kernel<<<dim3(NBLOCKS), dim3(THREADS), 0, stream>>>(
        (const f32x4*)map_memory, (const f32x4*)step_memory, (f32x4*)d_out,
        evidence, marker_id, source_idx, source_mask,
        target_symbol_idx, target_symbol_mask,
        target_value_idx, target_value_mask,
        map_W1, map_b1, map_W2, map_b2,
        step_W1, step_b1, step_W2, step_b2);
}